// Round 6
// baseline (258.261 us; speedup 1.0000x reference)
//
#include <hip/hip_runtime.h>
#include <hip/hip_bf16.h>
#include <math.h>

// Problem constants
#define J   21
#define NH  7
#define H   4
#define HD  64
#define ALPHA 0.2f

// LDS strides (elements)
#define HPS  264   // hp_bf row stride (shorts)
#define JPA  40    // attn_bf / x_bf row stride (shorts)
#define JPT  24    // h_t / h2_t row stride (shorts); quad3 b128 reads overlap next row:
                   // A-side k>=21 is exact zero so products vanish; LAST row spills into
                   // the zeroed 4-float tail.
#define JA2  32    // attn2_bf row stride (shorts): k 0..20 vals, 21..31 zeros
#define F12S 24    // f1/f2 per-head stride (floats)

// LDS map (floats), total 7932 f = 31728 B:
//   [0,2904)      hp_bf[22][HPS] shorts (s4 out / s5 A)
//                 post-s5 overlays: f1o@[0,21) ; f2o@[24,45) ; attn2_bf @ short-off 96
//                 = floats [48,400) ; sp[4][22] @ [400,488)
//   [2904,4664)   attn_bf[4][22][JPA] shorts (s3 out / s4 A); x_bf[22][JPA] overlay @ [2904,3344)
//   [4664,4856)   f1[4][F12S], f2[4][F12S] (s1b out / s3 in); p1@[4664,4752), p2@[4752,4840) overlay
//   [4856,7928)   h_t[256][JPT] shorts (s1 out / s4 B); h2_t[64][JPT] overlay (s5 out / s8 B)
//   [7928,7932)   tail pad — zeroed in s0 (quad3 spillover of last h_t row)
#define LDS_FLOATS 7932

typedef __attribute__((ext_vector_type(8))) short short8;
typedef __attribute__((ext_vector_type(4))) float floatx4;

static __device__ __forceinline__ short f2bf(float f) {          // RNE (preconv only)
    __hip_bfloat16 h = __float2bfloat16(f);
    return __builtin_bit_cast(short, h);
}
static __device__ __forceinline__ unsigned pack2hi(float lo, float hi) {
    // D = [hi16(hi) : hi16(lo)] in one v_perm_b32
    return __builtin_amdgcn_perm(__builtin_bit_cast(unsigned, hi),
                                 __builtin_bit_cast(unsigned, lo), 0x07060302u);
}
static __device__ __forceinline__ short hi16(float f) {          // truncating bf16
    return (short)(__builtin_bit_cast(unsigned, f) >> 16);
}
static __device__ __forceinline__ float elu(float a) {
    return (a > 0.f) ? a : (__expf(a) - 1.f);
}

// ---- pre-kernel: bf16 weight tables + wha fusion ----
// ws shorts: [0,16384)      WoT[n=64][k=256] = bf(Wo[k][n])
//            [16384,18432)  WhT[(h*64+d)][8] : n<7 -> bf(Wh[h][n][d]), n=7 -> 0
// ws floats @ short-offset 18432: wha[h][2][8] : wha[h][s][n] = sum_d Wh[h][n][d]*ah[h][s*64+d]
__global__ void preconv(const float* __restrict__ Wo, const float* __restrict__ Wh,
                        const float* __restrict__ ah, short* __restrict__ ws) {
    int t = blockIdx.x * 256 + threadIdx.x;
    if (t < 16384) {
        int n = t >> 8, k = t & 255;
        ws[t] = f2bf(Wo[k * HD + n]);
    } else if (t < 18432) {
        int i = t - 16384;
        int hh = i >> 9, d = (i >> 3) & 63, n = i & 7;
        ws[t] = (n < 7) ? f2bf(Wh[(hh * NH + n) * HD + d]) : (short)0;
    } else if (t < 18496) {
        int i = t - 18432;                 // 0..63
        int hh = i >> 4, s = (i >> 3) & 1, n = i & 7;
        float acc = 0.f;
        if (n < 7) {
            for (int d = 0; d < HD; d++)
                acc += Wh[(hh * NH + n) * HD + d] * ah[hh * 2 * HD + s * HD + d];
        }
        ((float*)(ws + 18432))[i] = acc;
    }
}

__global__ __launch_bounds__(256, 4)
void gat_kernel(const float* __restrict__ inp,
                const float* __restrict__ ao,   // (2*HD,)
                const short* __restrict__ ws,   // WoT + WhT + wha
                float* __restrict__ out)
{
    __shared__ __align__(16) float smem[LDS_FLOATS];
    short* hp_bf    = (short*)smem;                 // [22][HPS]
    float* f1o      = smem;                         // post-s5 overlays
    float* f2o      = smem + 24;
    short* attn2_bf = (short*)smem + 96;            // [22][JA2]
    float* sp       = smem + 400;                   // [4][22] exp partial sums
    short* attn_bf  = (short*)(smem + 2904);        // [4][22][JPA]
    short* x_bf     = (short*)(smem + 2904);        // [22][JPA] overlay
    float* f1       = smem + 4664;                  // [4][F12S]
    float* f2       = smem + 4760;
    float* p1       = smem + 4664;                  // [4][22] overlay (f1/f2 dead post-s3)
    float* p2       = smem + 4752;
    short* h_t      = (short*)(smem + 4856);        // [256][JPT]
    short* h2_t     = (short*)(smem + 4856);        // [64][JPT] overlay (h_t dead post-s4)

    const short* WoT  = ws;
    const short* WhT  = ws + 16384;
    const float* whaF = (const float*)(ws + 18432);

    const int t    = threadIdx.x;
    const int w    = t >> 6;          // wave = head = tile index
    const int lane = t & 63;
    const int quad = lane >> 4;
    const int col  = lane & 15;
    const int rc   = (16 + col < 21) ? (16 + col) : 21;   // clamped M1 A-row

    const size_t pair = blockIdx.x;
    const float* ip = inp + pair * (size_t)(J * NH);

    // ---- stage 0: write x_bf full rows (values + zeros) in b64 chunks; zero tail ----
    if (t < 220) {
        int row = t / 10, c4 = t - row * 10;
        unsigned lo = 0, hi = 0;
        if (row < 21) {
            if (c4 == 0) {
                float v0 = ip[row*3+0], v1 = ip[row*3+1], v2 = ip[row*3+2];
                float v3 = ip[63+row*3+0];
                lo = pack2hi(v0, v1); hi = pack2hi(v2, v3);
            } else if (c4 == 1) {
                float v4 = ip[63+row*3+1], v5 = ip[63+row*3+2], v6 = ip[126+row];
                lo = pack2hi(v4, v5); hi = pack2hi(v6, 0.f);
            }
        }
        *(uint2*)(x_bf + row * JPA + c4 * 4) = make_uint2(lo, hi);
    } else if (t < 224) {
        smem[7928 + (t - 220)] = 0.f;   // tail pad
    }
    __syncthreads();

    // ---- stage 1 (MFMA): h = x[21x7pad32] @ Wh_head[7x64] -> h_t bf16 (B-layout, b64-packed);
    //      1b: f1/f2 = x @ wha (fp32, from global) ----
    {
        short8 xa0 = *(const short8*)(x_bf + col * JPA + quad * 8);
        short8 xa1 = *(const short8*)(x_bf + rc  * JPA + quad * 8);
        floatx4 c0[4], c1[4];
        #pragma unroll
        for (int nt = 0; nt < 4; nt++) { c0[nt] = (floatx4){0,0,0,0}; c1[nt] = (floatx4){0,0,0,0}; }
        #pragma unroll
        for (int nt = 0; nt < 4; nt++) {
            short8 b = *(const short8*)(WhT + ((w * 64 + nt * 16 + col) << 3) + quad * 8);
            c0[nt] = __builtin_amdgcn_mfma_f32_16x16x32_bf16(xa0, b, c0[nt], 0, 0, 0);
            c1[nt] = __builtin_amdgcn_mfma_f32_16x16x32_bf16(xa1, b, c1[nt], 0, 0, 0);
        }
        #pragma unroll
        for (int nt = 0; nt < 4; nt++) {
            short* cb = h_t + (w * 64 + nt * 16 + col) * JPT;
            *(uint2*)(cb + quad * 4) =
                make_uint2(pack2hi(c0[nt][0], c0[nt][1]), pack2hi(c0[nt][2], c0[nt][3]));
            if (quad == 0)
                *(uint2*)(cb + 16) =
                    make_uint2(pack2hi(c1[nt][0], c1[nt][1]), pack2hi(c1[nt][2], c1[nt][3]));
            else if (quad == 1)
                *(uint2*)(cb + 20) = make_uint2(pack2hi(c1[nt][0], 0.f), 0u);
        }
        if (t < 84) {
            int hh = t / 21, j = t - hh * 21;
            float x0 = ip[j*3+0], x1 = ip[j*3+1], x2 = ip[j*3+2];
            float x3 = ip[63+j*3+0], x4 = ip[63+j*3+1], x5 = ip[63+j*3+2];
            float x6 = ip[126+j];
            const float* wp = whaF + hh * 16;
            f1[hh * F12S + j] = x0*wp[0] + x1*wp[1] + x2*wp[2] + x3*wp[3]
                              + x4*wp[4] + x5*wp[5] + x6*wp[6];
            f2[hh * F12S + j] = x0*wp[8] + x1*wp[9] + x2*wp[10] + x3*wp[11]
                              + x4*wp[12] + x5*wp[13] + x6*wp[14];
        }
    }
    __syncthreads();

    // ---- stage 3: attn[hh][i][:] = softmax_j( leaky_relu(f1[i]+f2[j]) ) -> bf16 rows;
    //      i == 21 writes an all-zero row ----
    if (t < H * 22) {
        int hh = t / 22, i = t % 22;
        unsigned* rowp = (unsigned*)(attn_bf + (hh * 22 + i) * JPA);
        if (i < J) {
            float fi = f1[hh * F12S + i];
            const float* f2r = f2 + hh * F12S;
            float ev[J];
            float m = -1e30f;
            #pragma unroll
            for (int c4 = 0; c4 < 5; c4++) {
                float4 fv = ((const float4*)f2r)[c4];
                float e;
                e = fi + fv.x; e = (e >= 0.f) ? e : ALPHA * e; ev[c4*4+0] = e; m = fmaxf(m, e);
                e = fi + fv.y; e = (e >= 0.f) ? e : ALPHA * e; ev[c4*4+1] = e; m = fmaxf(m, e);
                e = fi + fv.z; e = (e >= 0.f) ? e : ALPHA * e; ev[c4*4+2] = e; m = fmaxf(m, e);
                e = fi + fv.w; e = (e >= 0.f) ? e : ALPHA * e; ev[c4*4+3] = e; m = fmaxf(m, e);
            }
            { float e = fi + f2r[20]; e = (e >= 0.f) ? e : ALPHA * e; ev[20] = e; m = fmaxf(m, e); }
            float ssum = 0.f;
            #pragma unroll
            for (int j = 0; j < J; j++) { float ex = __expf(ev[j] - m); ev[j] = ex; ssum += ex; }
            float inv = 1.f / ssum;
            #pragma unroll
            for (int k = 0; k < 10; k++)
                rowp[k] = pack2hi(ev[2*k] * inv, ev[2*k+1] * inv);
            rowp[10] = pack2hi(ev[20] * inv, 0.f);
            #pragma unroll
            for (int k = 11; k < 16; k++) rowp[k] = 0;
        } else {
            #pragma unroll
            for (int k = 0; k < 16; k++) rowp[k] = 0;
        }
    }
    __syncthreads();

    // ---- stage 4 (MFMA): hp = attn[21x21pad32] @ h[21x64], ELU -> hp_bf (A-layout);
    //      zeroes hp row 21 ----
    {
        short8 aa0 = *(const short8*)(attn_bf + (w * 22 + col) * JPA + quad * 8);
        short8 aa1 = *(const short8*)(attn_bf + (w * 22 + rc)  * JPA + quad * 8);
        floatx4 c0[4], c1[4];
        #pragma unroll
        for (int nt = 0; nt < 4; nt++) { c0[nt] = (floatx4){0,0,0,0}; c1[nt] = (floatx4){0,0,0,0}; }
        #pragma unroll
        for (int nt = 0; nt < 4; nt++) {
            short8 b = *(const short8*)(h_t + (w * 64 + nt * 16 + col) * JPT + quad * 8);
            c0[nt] = __builtin_amdgcn_mfma_f32_16x16x32_bf16(aa0, b, c0[nt], 0, 0, 0);
            c1[nt] = __builtin_amdgcn_mfma_f32_16x16x32_bf16(aa1, b, c1[nt], 0, 0, 0);
        }
        #pragma unroll
        for (int nt = 0; nt < 4; nt++) {
            #pragma unroll
            for (int r = 0; r < 4; r++) {
                int row0 = quad * 4 + r;
                hp_bf[row0 * HPS + w * 64 + nt * 16 + col] = hi16(elu(c0[nt][r]));
                int row1 = 16 + quad * 4 + r;
                if (row1 < J)
                    hp_bf[row1 * HPS + w * 64 + nt * 16 + col] = hi16(elu(c1[nt][r]));
                else if (row1 == 21)
                    hp_bf[21 * HPS + w * 64 + nt * 16 + col] = 0;
            }
        }
    }
    __syncthreads();

    // ---- stage 5 (MFMA): h2 = hp[21x256] @ Wo[256x64] -> h2_t bf16 (B-layout, b64-packed);
    //      f1o/f2o partials from fp32 accumulators via 16-lane shfl ----
    {
        floatx4 d0 = {0,0,0,0}, d1 = {0,0,0,0};
        #pragma unroll
        for (int s = 0; s < 8; s++) {
            short8 a0 = *(const short8*)(hp_bf + col * HPS + s * 32 + quad * 8);
            short8 a1 = *(const short8*)(hp_bf + rc  * HPS + s * 32 + quad * 8);
            short8 b  = *(const short8*)(WoT + (w * 16 + col) * 256 + s * 32 + quad * 8);
            d0 = __builtin_amdgcn_mfma_f32_16x16x32_bf16(a0, b, d0, 0, 0, 0);
            d1 = __builtin_amdgcn_mfma_f32_16x16x32_bf16(a1, b, d1, 0, 0, 0);
        }
        short* cb = h2_t + (w * 16 + col) * JPT;
        *(uint2*)(cb + quad * 4) = make_uint2(pack2hi(d0[0], d0[1]), pack2hi(d0[2], d0[3]));
        if (quad == 0)
            *(uint2*)(cb + 16) = make_uint2(pack2hi(d1[0], d1[1]), pack2hi(d1[2], d1[3]));
        else if (quad == 1)
            *(uint2*)(cb + 20) = make_uint2(pack2hi(d1[0], 0.f), 0u);

        float aoc1 = ao[w * 16 + col];
        float aoc2 = ao[64 + w * 16 + col];
        #pragma unroll
        for (int r = 0; r < 4; r++) {
            float q10 = d0[r] * aoc1, q20 = d0[r] * aoc2;
            float q11 = d1[r] * aoc1, q21 = d1[r] * aoc2;
            #pragma unroll
            for (int off = 1; off < 16; off <<= 1) {
                q10 += __shfl_xor(q10, off);
                q20 += __shfl_xor(q20, off);
                q11 += __shfl_xor(q11, off);
                q21 += __shfl_xor(q21, off);
            }
            if (col == 0) {
                int row0 = quad * 4 + r;
                p1[w * 22 + row0] = q10; p2[w * 22 + row0] = q20;
                int row1 = 16 + quad * 4 + r;
                if (row1 < J) { p1[w * 22 + row1] = q11; p2[w * 22 + row1] = q21; }
            }
        }
    }
    __syncthreads();

    // ---- stage 6': reduce 4 wave-partials -> f1o/f2o ----
    if (t < 2 * J) {
        int which = t / J, j = t - which * J;
        const float* pp = which ? p2 : p1;
        float s = pp[j] + pp[22 + j] + pp[44 + j] + pp[66 + j];
        (which ? f2o : f1o)[j] = s;
    }
    __syncthreads();

    // ---- stage 7: attn2 rows = softmax_j( leaky_relu(f1o[i]+f2o[j]) ) -> bf16; row 21 zero ----
    if (t < 22) {
        unsigned* rowp = (unsigned*)(attn2_bf + t * JA2);
        if (t < J) {
            float fi = f1o[t];
            float ev[J];
            float m = -1e30f;
            #pragma unroll
            for (int c4 = 0; c4 < 5; c4++) {
                float4 fv = ((const float4*)f2o)[c4];
                float e;
                e = fi + fv.x; e = (e >= 0.f) ? e : ALPHA * e; ev[c4*4+0] = e; m = fmaxf(m, e);
                e = fi + fv.y; e = (e >= 0.f) ? e : ALPHA * e; ev[c4*4+1] = e; m = fmaxf(m, e);
                e = fi + fv.z; e = (e >= 0.f) ? e : ALPHA * e; ev[c4*4+2] = e; m = fmaxf(m, e);
                e = fi + fv.w; e = (e >= 0.f) ? e : ALPHA * e; ev[c4*4+3] = e; m = fmaxf(m, e);
            }
            { float e = fi + f2o[20]; e = (e >= 0.f) ? e : ALPHA * e; ev[20] = e; m = fmaxf(m, e); }
            float ssum = 0.f;
            #pragma unroll
            for (int j = 0; j < J; j++) { float ex = __expf(ev[j] - m); ev[j] = ex; ssum += ex; }
            float inv = 1.f / ssum;
            #pragma unroll
            for (int k = 0; k < 10; k++)
                rowp[k] = pack2hi(ev[2*k] * inv, ev[2*k+1] * inv);
            rowp[10] = pack2hi(ev[20] * inv, 0.f);
            #pragma unroll
            for (int k = 11; k < 16; k++) rowp[k] = 0;
        } else {
            #pragma unroll
            for (int k = 0; k < 16; k++) rowp[k] = 0;
        }
    }
    __syncthreads();

    // ---- stage 8 (MFMA): hp2 = attn2[21x21pad32] @ h2[21x64], ELU;
    //      log-softmax over d via 16-lane shfl + cross-wave LDS reduce; store ----
    {
        short8 a0 = *(const short8*)(attn2_bf + col * JA2 + quad * 8);
        short8 a1 = *(const short8*)(attn2_bf + rc  * JA2 + quad * 8);
        short8 b  = *(const short8*)(h2_t + (w * 16 + col) * JPT + quad * 8);
        floatx4 e0 = {0,0,0,0}, e1 = {0,0,0,0};
        e0 = __builtin_amdgcn_mfma_f32_16x16x32_bf16(a0, b, e0, 0, 0, 0);
        e1 = __builtin_amdgcn_mfma_f32_16x16x32_bf16(a1, b, e1, 0, 0, 0);

        float v0[4], v1[4];
        #pragma unroll
        for (int r = 0; r < 4; r++) {
            v0[r] = elu(e0[r]);
            v1[r] = elu(e1[r]);
            float ex0 = __expf(v0[r]);        // |v| bounded: no overflow without max pass
            float ex1 = __expf(v1[r]);
            #pragma unroll
            for (int off = 1; off < 16; off <<= 1) {
                ex0 += __shfl_xor(ex0, off);
                ex1 += __shfl_xor(ex1, off);
            }
            if (col == 0) {
                sp[w * 22 + quad * 4 + r] = ex0;
                int row1 = 16 + quad * 4 + r;
                if (row1 < J) sp[w * 22 + row1] = ex1;
            }
        }
        __syncthreads();

        float* outp = out + pair * (size_t)(J * HD);
        const int c = w * 16 + col;
        #pragma unroll
        for (int r = 0; r < 4; r++) {
            int row0 = quad * 4 + r;
            float S0 = sp[row0] + sp[22 + row0] + sp[44 + row0] + sp[66 + row0];
            outp[row0 * HD + c] = v0[r] - __logf(S0);
            int row1 = 16 + quad * 4 + r;
            if (row1 < J) {
                float S1 = sp[row1] + sp[22 + row1] + sp[44 + row1] + sp[66 + row1];
                outp[row1 * HD + c] = v1[r] - __logf(S1);
            }
        }
    }
}

extern "C" void kernel_launch(void* const* d_in, const int* in_sizes, int n_in,
                              void* d_out, int out_size, void* d_ws, size_t ws_size,
                              hipStream_t stream) {
    const float* inp = (const float*)d_in[0];
    // d_in[1] = seq_start_end (int64) — unused by the reference computation
    const float* Wh  = (const float*)d_in[2];
    const float* ah  = (const float*)d_in[3];
    const float* Wo  = (const float*)d_in[4];
    const float* ao  = (const float*)d_in[5];
    float* outp = (float*)d_out;
    short* ws   = (short*)d_ws;   // 18432 shorts + 64 floats = 37120 B

    hipLaunchKernelGGL(preconv, dim3(73), dim3(256), 0, stream, Wo, Wh, ah, ws);

    const int pairs = in_sizes[0] / (J * NH);  // 16384
    hipLaunchKernelGGL(gat_kernel, dim3(pairs), dim3(256), 0, stream,
                       inp, ao, (const short*)ws, outp);
}

// Round 7
// 225.152 us; speedup vs baseline: 1.1470x; 1.1470x over previous
//
#include <hip/hip_runtime.h>
#include <hip/hip_bf16.h>
#include <math.h>

// Problem constants
#define J   21
#define NH  7
#define H   4
#define HD  64
#define ALPHA 0.2f

// LDS strides (in elements)
#define HPS  264   // hp_bf row stride (shorts)
#define JPA  40    // attn_bf / x_bf row stride (shorts)
#define JPT  24    // h_t / h2_t row stride (shorts); quad3 b128 reads overlap next row:
                   // safe because the A-side is exact zero for k>=21 (products vanish) and
                   // overlapped data is finite bf16; the very last row spills into zeroed tail
                   // (h_t) or dead-but-finite h_t leftovers (h2_t).
#define JA2  32    // attn2_bf row stride (shorts): k 0..20 vals, 21..31 zeros (exact 32, no spill)
#define F12S 24    // f1/f2 per-head stride (floats)
#define A2S  24    // (legacy, unused)

// LDS map (floats), total 7932 f = 31728 B:
//   [0,2904)      hp_bf[22][HPS] shorts (s4 out / s5 A)
//                 post-s5 overlays: f1o@[0,21) ; f2o@[24,45) ; attn2_bf @ short-off 96 = floats [48,400)
//   [2904,4664)   attn_bf[4][22][JPA] shorts (s3 out / s4 A); xs_raw[147] + x_bf overlays (s0/s1)
//   [4664,4856)   f1[4][F12S], f2[4][F12S]
//   [4856,6284)   h2[21][68] fp32 (s5 out / s6 in) — overlays dead h_t
//   [4856,7928)   h_t[256][JPT] shorts (s1 out / s4 B)
//   [6300,7068)   h2_t[64][JPT] shorts (s5 out / s8 B) — also overlays dead h_t
//   [7928,7932)   tail pad — zeroed in s0
#define ROW2 68
#define LDS_FLOATS 7932

typedef __attribute__((ext_vector_type(8))) short short8;
typedef __attribute__((ext_vector_type(4))) float floatx4;

static __device__ __forceinline__ short f2bf(float f) {          // RNE (preconv only)
    __hip_bfloat16 h = __float2bfloat16(f);
    return __builtin_bit_cast(short, h);
}
static __device__ __forceinline__ short hi16(float f) {          // truncating bf16 (cheap)
    return (short)(__builtin_bit_cast(unsigned, f) >> 16);
}
static __device__ __forceinline__ unsigned pack2hi(float lo, float hi) {
    // D = [hi16(hi) : hi16(lo)] in one v_perm_b32
    return __builtin_amdgcn_perm(__builtin_bit_cast(unsigned, hi),
                                 __builtin_bit_cast(unsigned, lo), 0x07060302u);
}
static __device__ __forceinline__ float elu(float a) {
    return (a > 0.f) ? a : (__expf(a) - 1.f);
}

// ---- pre-kernel: bf16 weight tables + wha fusion ----
// ws shorts: [0,16384)      WoT[n=64][k=256] = bf(Wo[k][n])
//            [16384,18432)  WhT[(h*64+d)][8] : n<7 -> bf(Wh[h][n][d]), n=7 -> 0
// ws floats @ short-offset 18432: wha[h][2][8] : wha[h][s][n] = sum_d Wh[h][n][d]*ah[h][s*64+d]
__global__ void preconv(const float* __restrict__ Wo, const float* __restrict__ Wh,
                        const float* __restrict__ ah, short* __restrict__ ws) {
    int t = blockIdx.x * 256 + threadIdx.x;
    if (t < 16384) {
        int n = t >> 8, k = t & 255;
        ws[t] = f2bf(Wo[k * HD + n]);
    } else if (t < 18432) {
        int i = t - 16384;
        int hh = i >> 9, d = (i >> 3) & 63, n = i & 7;
        ws[t] = (n < 7) ? f2bf(Wh[(hh * NH + n) * HD + d]) : (short)0;
    } else if (t < 18496) {
        int i = t - 18432;                 // 0..63
        int hh = i >> 4, s = (i >> 3) & 1, n = i & 7;
        float acc = 0.f;
        if (n < 7) {
            for (int d = 0; d < HD; d++)
                acc += Wh[(hh * NH + n) * HD + d] * ah[hh * 2 * HD + s * HD + d];
        }
        ((float*)(ws + 18432))[i] = acc;
    }
}

__global__ __launch_bounds__(256, 4)
void gat_kernel(const float* __restrict__ inp,
                const float* __restrict__ ao,   // (2*HD,)
                const short* __restrict__ ws,   // WoT + WhT + wha
                float* __restrict__ out)
{
    __shared__ __align__(16) float smem[LDS_FLOATS];
    short* hp_bf    = (short*)smem;                 // [22][HPS]
    float* xs_raw   = smem + 2904;                  // [147] raw inputs (s0/s1b; dead before s3 write)
    float* f1o      = smem;                         // post-s5 overlays of hp region
    float* f2o      = smem + 24;
    short* attn2_bf = (short*)smem + 96;            // [22][JA2] floats [48,400)
    short* attn_bf  = (short*)(smem + 2904);        // [4][22][JPA]
    float* f1       = smem + 4664;                  // [4][F12S]
    float* f2       = smem + 4760;
    short* h_t      = (short*)(smem + 4856);        // [256][JPT]
    float* h2       = smem + 4856;                  // [21][ROW2] fp32 (overlays dead h_t)
    short* h2_t     = (short*)(smem + 6300);        // [64][JPT] (overlays dead h_t)

    const short* WoT  = ws;
    const short* WhT  = ws + 16384;
    const float* whaF = (const float*)(ws + 18432);

    const int t    = threadIdx.x;
    const int w    = t >> 6;          // wave = head = tile index
    const int lane = t & 63;
    const int quad = lane >> 4;
    const int col  = lane & 15;
    const int rc   = (16 + col < 21) ? (16 + col) : 21;   // clamped M1 A-row

    const size_t pair = blockIdx.x;
    const float* ip = inp + pair * (size_t)(J * NH);

    // ---- stage 0: zero x_bf region (attn_bf floats [2904,3344) minus xs_raw? full 440) + tail;
    //      NOTE: xs_raw occupies [2904,3051) and is re-purposed: we zero [2904,3344) FIRST,
    //      then write xs_raw/x_bf after the barrier below? To keep R5 semantics exactly:
    //      x_bf (bf16 A-tiles) lives in shorts of [2904,3344); xs_raw shares the first 147
    //      floats. R5 zeroed all 440 floats then scattered — replicate that. ----
    for (int e = t; e < 440; e += 256) smem[2904 + e] = 0.f;
    if (t < 4) smem[7928 + t] = 0.f;   // tail pad
    __syncthreads();
    if (t < J * NH) {
        float v = ip[t];
        int j, k;
        if (t < 63)       { j = t / 3;        k = t % 3; }
        else if (t < 126) { j = (t - 63) / 3; k = 3 + (t - 63) % 3; }
        else              { j = t - 126;      k = 6; }
        // x_bf element [j][k] at short index j*JPA + k within [2904..) region,
        // but shorts 0..293 alias xs_raw floats 0..146. Avoid aliasing: x_bf rows start
        // at short offset 640 (float 320): rows [0..21] * JPA = up to 880 shorts < (440-320)*2=240? No.
        // R5 layout: x_bf == (short*)(smem+2904) directly and xs_raw was at smem+0 (hp region).
        ((short*)(smem + 2904))[j * JPA + k] = hi16(v);
        smem[0 + t] = v;               // xs_raw in hp region (dead until s4) — R5 behavior
    }
    __syncthreads();

    // ---- stage 1 (MFMA): h = x[21x7pad32] @ Wh_head[7x64] -> h_t bf16 (B-layout);
    //      1b: f1/f2 = x @ wha (fp32) ----
    {
        const short* x_bf = (const short*)(smem + 2904);
        short8 xa0 = *(const short8*)(x_bf + col * JPA + quad * 8);
        short8 xa1 = *(const short8*)(x_bf + rc  * JPA + quad * 8);
        floatx4 c0[4], c1[4];
        #pragma unroll
        for (int nt = 0; nt < 4; nt++) { c0[nt] = (floatx4){0,0,0,0}; c1[nt] = (floatx4){0,0,0,0}; }
        #pragma unroll
        for (int nt = 0; nt < 4; nt++) {
            short8 b = *(const short8*)(WhT + ((w * 64 + nt * 16 + col) << 3) + quad * 8);
            c0[nt] = __builtin_amdgcn_mfma_f32_16x16x32_bf16(xa0, b, c0[nt], 0, 0, 0);
            c1[nt] = __builtin_amdgcn_mfma_f32_16x16x32_bf16(xa1, b, c1[nt], 0, 0, 0);
        }
        #pragma unroll
        for (int nt = 0; nt < 4; nt++) {
            short* colbase = h_t + (w * 64 + nt * 16 + col) * JPT;
            #pragma unroll
            for (int r = 0; r < 4; r++) {
                colbase[quad * 4 + r] = hi16(c0[nt][r]);
                int row1 = 16 + quad * 4 + r;
                if (row1 < J) colbase[row1] = hi16(c1[nt][r]);
                else if (row1 < JPT) colbase[row1] = 0;
            }
        }
        if (t < 84) {
            int hh = t / 21, j = t - hh * 21;
            const float* xr = smem;    // xs_raw in hp region
            float x0 = xr[j*3+0], x1 = xr[j*3+1], x2 = xr[j*3+2];
            float x3 = xr[63+j*3+0], x4 = xr[63+j*3+1], x5 = xr[63+j*3+2];
            float x6 = xr[126+j];
            const float* wp = whaF + hh * 16;
            f1[hh * F12S + j] = x0*wp[0] + x1*wp[1] + x2*wp[2] + x3*wp[3]
                              + x4*wp[4] + x5*wp[5] + x6*wp[6];
            f2[hh * F12S + j] = x0*wp[8] + x1*wp[9] + x2*wp[10] + x3*wp[11]
                              + x4*wp[12] + x5*wp[13] + x6*wp[14];
        }
    }
    __syncthreads();

    // ---- stage 3: attn rows = softmax_j( leaky_relu(f1[i]+f2[j]) ) -> bf16; row 21 zeroed ----
    if (t < H * 22) {
        int hh = t / 22, i = t % 22;
        unsigned* rowp = (unsigned*)(attn_bf + (hh * 22 + i) * JPA);
        if (i < J) {
            float fi = f1[hh * F12S + i];
            const float* f2r = f2 + hh * F12S;
            float ev[J];
            float m = -1e30f;
            #pragma unroll
            for (int c4 = 0; c4 < 5; c4++) {
                float4 fv = ((const float4*)f2r)[c4];
                float e;
                e = fi + fv.x; e = (e >= 0.f) ? e : ALPHA * e; ev[c4*4+0] = e; m = fmaxf(m, e);
                e = fi + fv.y; e = (e >= 0.f) ? e : ALPHA * e; ev[c4*4+1] = e; m = fmaxf(m, e);
                e = fi + fv.z; e = (e >= 0.f) ? e : ALPHA * e; ev[c4*4+2] = e; m = fmaxf(m, e);
                e = fi + fv.w; e = (e >= 0.f) ? e : ALPHA * e; ev[c4*4+3] = e; m = fmaxf(m, e);
            }
            { float e = fi + f2r[20]; e = (e >= 0.f) ? e : ALPHA * e; ev[20] = e; m = fmaxf(m, e); }
            float ssum = 0.f;
            #pragma unroll
            for (int j = 0; j < J; j++) { float ex = __expf(ev[j] - m); ev[j] = ex; ssum += ex; }
            float inv = 1.f / ssum;
            #pragma unroll
            for (int k = 0; k < 10; k++)
                rowp[k] = pack2hi(ev[2*k] * inv, ev[2*k+1] * inv);
            rowp[10] = pack2hi(ev[20] * inv, 0.f);
            #pragma unroll
            for (int k = 11; k < 16; k++) rowp[k] = 0;
        } else {
            #pragma unroll
            for (int k = 0; k < 16; k++) rowp[k] = 0;
        }
    }
    __syncthreads();

    // ---- stage 4 (MFMA): hp = attn[21x21pad32] @ h[21x64], ELU -> hp_bf (A-layout);
    //      zeroes hp row 21 ----
    {
        short8 aa0 = *(const short8*)(attn_bf + (w * 22 + col) * JPA + quad * 8);
        short8 aa1 = *(const short8*)(attn_bf + (w * 22 + rc)  * JPA + quad * 8);
        floatx4 c0[4], c1[4];
        #pragma unroll
        for (int nt = 0; nt < 4; nt++) { c0[nt] = (floatx4){0,0,0,0}; c1[nt] = (floatx4){0,0,0,0}; }
        #pragma unroll
        for (int nt = 0; nt < 4; nt++) {
            short8 b = *(const short8*)(h_t + (w * 64 + nt * 16 + col) * JPT + quad * 8);
            c0[nt] = __builtin_amdgcn_mfma_f32_16x16x32_bf16(aa0, b, c0[nt], 0, 0, 0);
            c1[nt] = __builtin_amdgcn_mfma_f32_16x16x32_bf16(aa1, b, c1[nt], 0, 0, 0);
        }
        #pragma unroll
        for (int nt = 0; nt < 4; nt++) {
            #pragma unroll
            for (int r = 0; r < 4; r++) {
                int row0 = quad * 4 + r;
                hp_bf[row0 * HPS + w * 64 + nt * 16 + col] = hi16(elu(c0[nt][r]));
                int row1 = 16 + quad * 4 + r;
                if (row1 < J)
                    hp_bf[row1 * HPS + w * 64 + nt * 16 + col] = hi16(elu(c1[nt][r]));
                else if (row1 == 21)
                    hp_bf[21 * HPS + w * 64 + nt * 16 + col] = 0;
            }
        }
    }
    __syncthreads();

    // ---- stage 5 (MFMA): h2 = hp[21x256] @ Wo[256x64] -> h2 fp32 (s6) AND h2_t bf16 (s8) ----
    {
        floatx4 d0 = {0,0,0,0}, d1 = {0,0,0,0};
        #pragma unroll
        for (int s = 0; s < 8; s++) {
            short8 a0 = *(const short8*)(hp_bf + col * HPS + s * 32 + quad * 8);
            short8 a1 = *(const short8*)(hp_bf + rc  * HPS + s * 32 + quad * 8);
            short8 b  = *(const short8*)(WoT + (w * 16 + col) * 256 + s * 32 + quad * 8);
            d0 = __builtin_amdgcn_mfma_f32_16x16x32_bf16(a0, b, d0, 0, 0, 0);
            d1 = __builtin_amdgcn_mfma_f32_16x16x32_bf16(a1, b, d1, 0, 0, 0);
        }
        const int c = w * 16 + col;
        #pragma unroll
        for (int r = 0; r < 4; r++) {
            h2[(quad * 4 + r) * ROW2 + c] = d0[r];
            int row1 = 16 + quad * 4 + r;
            if (row1 < J) h2[row1 * ROW2 + c] = d1[r];
        }
        // h2_t bf16 (B-layout [n][m]) packed stores for stage 8
        short* cb = h2_t + c * JPT;
        *(uint2*)(cb + quad * 4) = make_uint2(pack2hi(d0[0], d0[1]), pack2hi(d0[2], d0[3]));
        if (quad == 0)
            *(uint2*)(cb + 16) = make_uint2(pack2hi(d1[0], d1[1]), pack2hi(d1[2], d1[3]));
        else if (quad == 1)
            *(uint2*)(cb + 20) = make_uint2(pack2hi(d1[0], 0.f), 0u);
    }
    __syncthreads();

    // ---- stage 6: f1o[j] = h2[j][:].ao[:64], f2o[j] = h2[j][:].ao[64:] ----
    if (t < 2 * J) {
        int which = t / J, j = t % J;
        const float4* hrow = (const float4*)(h2 + j * ROW2);
        const float4* ap   = (const float4*)(ao + which * HD);
        float sacc = 0.f;
        #pragma unroll
        for (int k = 0; k < HD / 4; k++) {
            float4 hv = hrow[k], av = ap[k];
            sacc += hv.x*av.x + hv.y*av.y + hv.z*av.z + hv.w*av.w;
        }
        if (which == 0) f1o[j] = sacc; else f2o[j] = sacc;
    }
    __syncthreads();

    // ---- stage 7: attn2 rows = softmax_j( leaky_relu(f1o[i]+f2o[j]) ) -> bf16; row 21 zero ----
    if (t < 22) {
        unsigned* rowp = (unsigned*)(attn2_bf + t * JA2);
        if (t < J) {
            float fi = f1o[t];
            float ev[J];
            float m = -1e30f;
            #pragma unroll
            for (int c4 = 0; c4 < 5; c4++) {
                float4 fv = ((const float4*)f2o)[c4];
                float e;
                e = fi + fv.x; e = (e >= 0.f) ? e : ALPHA * e; ev[c4*4+0] = e; m = fmaxf(m, e);
                e = fi + fv.y; e = (e >= 0.f) ? e : ALPHA * e; ev[c4*4+1] = e; m = fmaxf(m, e);
                e = fi + fv.z; e = (e >= 0.f) ? e : ALPHA * e; ev[c4*4+2] = e; m = fmaxf(m, e);
                e = fi + fv.w; e = (e >= 0.f) ? e : ALPHA * e; ev[c4*4+3] = e; m = fmaxf(m, e);
            }
            { float e = fi + f2o[20]; e = (e >= 0.f) ? e : ALPHA * e; ev[20] = e; m = fmaxf(m, e); }
            float ssum = 0.f;
            #pragma unroll
            for (int j = 0; j < J; j++) { float ex = __expf(ev[j] - m); ev[j] = ex; ssum += ex; }
            float inv = 1.f / ssum;
            #pragma unroll
            for (int k = 0; k < 10; k++)
                rowp[k] = pack2hi(ev[2*k] * inv, ev[2*k+1] * inv);
            rowp[10] = pack2hi(ev[20] * inv, 0.f);
            #pragma unroll
            for (int k = 11; k < 16; k++) rowp[k] = 0;
        } else {
            #pragma unroll
            for (int k = 0; k < 16; k++) rowp[k] = 0;
        }
    }
    __syncthreads();

    // ---- stage 8 (MFMA, barrier-free): hp2 = attn2[21x21pad32] @ h2[21x64], ELU,
    //      log-softmax over d entirely in-wave (each wave holds full rows), store.
    //      Wave w: M-tile = w&1; waves w and w+2 duplicate the MFMAs but finalize
    //      different r-pairs (r = (w>>1)*2 + {0,1}). ----
    {
        const int mt = w & 1;
        const int rh = w >> 1;
        const int arow = mt * 16 + col;
        const int ar = (arow < 21) ? arow : 21;            // row 21 is all-zero
        short8 a = *(const short8*)(attn2_bf + ar * JA2 + quad * 8);
        floatx4 acc[4];
        #pragma unroll
        for (int nt = 0; nt < 4; nt++) {
            short8 b = *(const short8*)(h2_t + (nt * 16 + col) * JPT + quad * 8);
            floatx4 z = {0,0,0,0};
            acc[nt] = __builtin_amdgcn_mfma_f32_16x16x32_bf16(a, b, z, 0, 0, 0);
        }
        float* outp = out + pair * (size_t)(J * HD);
        #pragma unroll
        for (int rr = 0; rr < 2; rr++) {
            int r = rh * 2 + rr;
            int row = mt * 16 + quad * 4 + r;
            float v0 = elu(acc[0][r]), v1 = elu(acc[1][r]);
            float v2 = elu(acc[2][r]), v3 = elu(acc[3][r]);
            float s = __expf(v0) + __expf(v1) + __expf(v2) + __expf(v3);
            s += __shfl_xor(s, 1);
            s += __shfl_xor(s, 2);
            s += __shfl_xor(s, 4);
            s += __shfl_xor(s, 8);
            float ls = __logf(s);
            if (row < J) {
                outp[row * HD +      col] = v0 - ls;
                outp[row * HD + 16 + col] = v1 - ls;
                outp[row * HD + 32 + col] = v2 - ls;
                outp[row * HD + 48 + col] = v3 - ls;
            }
        }
    }
}

extern "C" void kernel_launch(void* const* d_in, const int* in_sizes, int n_in,
                              void* d_out, int out_size, void* d_ws, size_t ws_size,
                              hipStream_t stream) {
    const float* inp = (const float*)d_in[0];
    // d_in[1] = seq_start_end (int64) — unused by the reference computation
    const float* Wh  = (const float*)d_in[2];
    const float* ah  = (const float*)d_in[3];
    const float* Wo  = (const float*)d_in[4];
    const float* ao  = (const float*)d_in[5];
    float* outp = (float*)d_out;
    short* ws   = (short*)d_ws;   // 18432 shorts + 64 floats = 37120 B

    hipLaunchKernelGGL(preconv, dim3(73), dim3(256), 0, stream, Wo, Wh, ah, ws);

    const int pairs = in_sizes[0] / (J * NH);  // 16384
    hipLaunchKernelGGL(gat_kernel, dim3(pairs), dim3(256), 0, stream,
                       inp, ao, (const short*)ws, outp);
}